// Round 8
// baseline (254.645 us; speedup 1.0000x reference)
//
#include <hip/hip_runtime.h>

#define K_SEGS 8192
#define ALPHA_W 0.5f
#define NEG_INF_BITS 0xFF800000
#define WIN 64            // id window per block (chunk spans ~5 ids; 64 = 12x margin)
#define NBLOCKS 2048
#define BLOCK 256

// ws layout (unsigned words):
//   [0      .. 8191 ]  seg_sum  (float)
//   [8192   .. 16383]  seg_maxb (unsigned float-bits; init 0 valid since loss >= 0)
//   [16384  .. 24575]  seg_cnt  (unsigned; #blocks touching -> presence)
//   [24576]            ticket
#define WS_WORDS (3 * K_SEGS + 1)

// ---------------------------------------------------------------------------
// Kernel 0: zero the accumulators + ticket (ws poisoned 0xAA, never re-poisoned)
// ---------------------------------------------------------------------------
__global__ void init_ws_kernel(unsigned* __restrict__ w) {
    int i = blockIdx.x * blockDim.x + threadIdx.x;
    if (i < WS_WORDS) w[i] = 0u;
}

// ---------------------------------------------------------------------------
// focal loss for one node given its 8 logits + target
// ---------------------------------------------------------------------------
__device__ __forceinline__ float node_focal(float4 a, float4 b, int t) {
    float x0 = a.x, x1 = a.y, x2 = a.z, x3 = a.w;
    float x4 = b.x, x5 = b.y, x6 = b.z, x7 = b.w;
    float m = fmaxf(fmaxf(fmaxf(x0, x1), fmaxf(x2, x3)),
                    fmaxf(fmaxf(x4, x5), fmaxf(x6, x7)));
    float s = __expf(x0 - m) + __expf(x1 - m) + __expf(x2 - m) + __expf(x3 - m)
            + __expf(x4 - m) + __expf(x5 - m) + __expf(x6 - m) + __expf(x7 - m);
    float lse = __logf(s) + m;
    float xt;
    switch (t) {
        case 0: xt = x0; break; case 1: xt = x1; break;
        case 2: xt = x2; break; case 3: xt = x3; break;
        case 4: xt = x4; break; case 5: xt = x5; break;
        case 6: xt = x6; break; default: xt = x7; break;
    }
    float ce = lse - xt;              // >= 0
    float pt = __expf(-ce);           // (0, 1]
    float om = 1.0f - pt;
    return om * om * ce;              // >= 0
}

// ---------------------------------------------------------------------------
// Kernel 1 (fused): focal loss + LDS-privatized segmented sum/max + last-block
// finalize via ticket. Each block owns a contiguous node chunk (sorted cid).
// ---------------------------------------------------------------------------
__global__ __launch_bounds__(BLOCK) void node_loss_kernel(
        const float* __restrict__ logits,   // [N, 8]
        const int* __restrict__ targets,    // [N]
        const int* __restrict__ cid,        // [N], sorted
        float* __restrict__ seg_sum,        // [K]
        unsigned* __restrict__ seg_maxb,    // [K]
        unsigned* __restrict__ seg_cnt,     // [K]
        unsigned* __restrict__ ticket,
        float* __restrict__ out,
        int n) {
    __shared__ float lsum[WIN];
    __shared__ int   lmax[WIN];
    __shared__ unsigned s_old;
    __shared__ float s_fa[4], s_fn[4];

    const int tid  = threadIdx.x;
    const int lane = tid & 63;

    const int chunk  = (n + NBLOCKS - 1) / NBLOCKS;   // 1954 for N=4M (even)
    const int cstart = blockIdx.x * chunk;

    if (cstart < n) {
        const int cend = min(cstart + chunk, n);
        const int base = cid[cstart];                 // broadcast load

        for (int j = tid; j < WIN; j += BLOCK) {
            lsum[j] = 0.0f;
            lmax[j] = (int)NEG_INF_BITS;
        }
        __syncthreads();

        // 2 nodes/thread; wave covers 128 consecutive nodes/iter.
        for (int i0 = cstart + tid * 2; __any(i0 < cend); i0 += BLOCK * 2) {
            bool v0 = (i0 < cend);
            bool v1 = (i0 + 1 < cend);
            float la = 0.0f, lb = 0.0f;
            int offa = -1, offb = -2;
            if (v0) {
                const float4* lg = reinterpret_cast<const float4*>(logits) + (size_t)i0 * 2;
                float4 a0 = lg[0];
                float4 a1 = lg[1];
                float4 b0, b1;
                int ta, tb = 0;
                if (v1) {
                    b0 = lg[2];
                    b1 = lg[3];
                    int2 tt = *reinterpret_cast<const int2*>(targets + i0);  // i0 even
                    int2 cc = *reinterpret_cast<const int2*>(cid + i0);
                    ta = tt.x; tb = tt.y;
                    offa = cc.x - base;
                    offb = cc.y - base;
                } else {
                    ta = targets[i0];
                    offa = cid[i0] - base;
                }
                la = node_focal(a0, a1, ta);
                if (v1) lb = node_focal(b0, b1, tb);
            }

            int u = __shfl(offa, 0);
            bool uniform = __all(offa == u && offb == u) && (u < WIN);
            if (uniform) {
                // all 128 nodes one segment: pair-combine then one butterfly
                float tsum = la + lb;
                float tmax = fmaxf(la, lb);
                #pragma unroll
                for (int o = 32; o > 0; o >>= 1) {
                    tsum += __shfl_xor(tsum, o);
                    tmax = fmaxf(tmax, __shfl_xor(tmax, o));
                }
                if (lane == 0) {
                    atomicAdd(&lsum[u], tsum);
                    atomicMax(&lmax[u], __float_as_int(tmax));
                }
            } else {
                if (v0) {
                    if (offa < WIN) {
                        atomicAdd(&lsum[offa], la);
                        atomicMax(&lmax[offa], __float_as_int(la));
                    } else {  // pathological overflow: direct global accumulate
                        atomicAdd(&seg_sum[base + offa], la);
                        atomicMax(&seg_maxb[base + offa], __float_as_uint(la));
                        atomicAdd(&seg_cnt[base + offa], 1u);
                    }
                }
                if (v1) {
                    if (offb < WIN) {
                        atomicAdd(&lsum[offb], lb);
                        atomicMax(&lmax[offb], __float_as_int(lb));
                    } else {
                        atomicAdd(&seg_sum[base + offb], lb);
                        atomicMax(&seg_maxb[base + offb], __float_as_uint(lb));
                        atomicAdd(&seg_cnt[base + offb], 1u);
                    }
                }
            }
        }
        __syncthreads();

        // flush touched window entries: ~5-10 global atomic triples per block
        for (int j = tid; j < WIN; j += BLOCK) {
            int mb = lmax[j];
            if (mb != (int)NEG_INF_BITS) {
                atomicAdd(&seg_sum[base + j], lsum[j]);
                atomicMax(&seg_maxb[base + j], (unsigned)mb);  // mb >= 0 (nonneg float bits)
                atomicAdd(&seg_cnt[base + j], 1u);
            }
        }
    }

    // ---- ticket: last finished block runs the finalize ----
    __threadfence();              // each thread: own flush atomics visible device-wide
    __syncthreads();              // whole block fenced
    if (tid == 0) s_old = atomicAdd(ticket, 1u);
    __syncthreads();
    if (s_old == (unsigned)(NBLOCKS - 1)) {
        __threadfence();
        float acc = 0.0f, np = 0.0f;
        for (int k = tid; k < K_SEGS; k += BLOCK) {
            // device-scope atomic loads: force coherence-point reads (per-XCD L2
            // is not cross-coherent; plain loads could see stale lines)
            unsigned c = __hip_atomic_load(&seg_cnt[k], __ATOMIC_RELAXED, __HIP_MEMORY_SCOPE_AGENT);
            if (c != 0u) {
                float s    = __hip_atomic_load(&seg_sum[k],  __ATOMIC_RELAXED, __HIP_MEMORY_SCOPE_AGENT);
                unsigned m = __hip_atomic_load(&seg_maxb[k], __ATOMIC_RELAXED, __HIP_MEMORY_SCOPE_AGENT);
                acc += ALPHA_W * s + (1.0f - ALPHA_W) * __uint_as_float(m);
                np += 1.0f;
            }
        }
        #pragma unroll
        for (int o = 32; o > 0; o >>= 1) {
            acc += __shfl_xor(acc, o);
            np  += __shfl_xor(np, o);
        }
        if (lane == 0) { s_fa[tid >> 6] = acc; s_fn[tid >> 6] = np; }
        __syncthreads();
        if (tid == 0) {
            float a = s_fa[0] + s_fa[1] + s_fa[2] + s_fa[3];
            float c = s_fn[0] + s_fn[1] + s_fn[2] + s_fn[3];
            out[0] = a / fmaxf(c, 1.0f);
        }
    }
}

// ---------------------------------------------------------------------------
extern "C" void kernel_launch(void* const* d_in, const int* in_sizes, int n_in,
                              void* d_out, int out_size, void* d_ws, size_t ws_size,
                              hipStream_t stream) {
    const float* logits = (const float*)d_in[0];
    const int* targets  = (const int*)d_in[1];
    const int* cid      = (const int*)d_in[2];
    float* out          = (float*)d_out;

    const int n = in_sizes[1];   // N = 4,000,000

    unsigned* w        = (unsigned*)d_ws;
    float* seg_sum     = (float*)w;
    unsigned* seg_maxb = w + K_SEGS;
    unsigned* seg_cnt  = w + 2 * K_SEGS;
    unsigned* ticket   = w + 3 * K_SEGS;

    init_ws_kernel<<<(WS_WORDS + 255) / 256, 256, 0, stream>>>(w);

    node_loss_kernel<<<NBLOCKS, BLOCK, 0, stream>>>(logits, targets, cid,
                                                    seg_sum, seg_maxb, seg_cnt,
                                                    ticket, out, n);
}

// Round 9
// 67.679 us; speedup vs baseline: 3.7625x; 3.7625x over previous
//
#include <hip/hip_runtime.h>

#define K_SEGS 8192
#define ALPHA_W 0.5f
#define NEG_INF_BITS 0xFF800000
#define WIN 64            // id window per block (chunk spans ~5 ids; 64 = 12x margin)
#define NBLOCKS 2048
#define BLOCK 256

// ws layout (unsigned words):
//   [0      .. 8191 ]  seg_sum  (float)
//   [8192   .. 16383]  seg_maxb (unsigned float-bits; init 0 valid since loss >= 0)
//   [16384  .. 24575]  seg_cnt  (unsigned; #blocks touching -> presence)
//   [24576]            ticket
#define WS_WORDS (3 * K_SEGS + 1)

// ---------------------------------------------------------------------------
// Kernel 0: zero the accumulators + ticket (ws poisoned 0xAA, never re-poisoned)
// ---------------------------------------------------------------------------
__global__ void init_ws_kernel(unsigned* __restrict__ w) {
    int i = blockIdx.x * blockDim.x + threadIdx.x;
    if (i < WS_WORDS) w[i] = 0u;
}

// ---------------------------------------------------------------------------
// focal loss for one node given its 8 logits + target
// ---------------------------------------------------------------------------
__device__ __forceinline__ float node_focal(float4 a, float4 b, int t) {
    float x0 = a.x, x1 = a.y, x2 = a.z, x3 = a.w;
    float x4 = b.x, x5 = b.y, x6 = b.z, x7 = b.w;
    float m = fmaxf(fmaxf(fmaxf(x0, x1), fmaxf(x2, x3)),
                    fmaxf(fmaxf(x4, x5), fmaxf(x6, x7)));
    float s = __expf(x0 - m) + __expf(x1 - m) + __expf(x2 - m) + __expf(x3 - m)
            + __expf(x4 - m) + __expf(x5 - m) + __expf(x6 - m) + __expf(x7 - m);
    float lse = __logf(s) + m;
    float xt;
    switch (t) {
        case 0: xt = x0; break; case 1: xt = x1; break;
        case 2: xt = x2; break; case 3: xt = x3; break;
        case 4: xt = x4; break; case 5: xt = x5; break;
        case 6: xt = x6; break; default: xt = x7; break;
    }
    float ce = lse - xt;              // >= 0
    float pt = __expf(-ce);           // (0, 1]
    float om = 1.0f - pt;
    return om * om * ce;              // >= 0
}

// ---------------------------------------------------------------------------
// Kernel 1 (fused, fence-free): focal loss + LDS-privatized segmented sum/max
// + last-block finalize via ticket. All cross-block traffic is device-scope
// atomics (coherence-point); __syncthreads' vmcnt drain orders flush->ticket.
// NO __threadfence (agent fence = per-wave L2 writeback storm, +350us in R8).
// ---------------------------------------------------------------------------
__global__ __launch_bounds__(BLOCK) void node_loss_kernel(
        const float* __restrict__ logits,   // [N, 8]
        const int* __restrict__ targets,    // [N]
        const int* __restrict__ cid,        // [N], sorted
        float* __restrict__ seg_sum,        // [K]
        unsigned* __restrict__ seg_maxb,    // [K]
        unsigned* __restrict__ seg_cnt,     // [K]
        unsigned* __restrict__ ticket,
        float* __restrict__ out,
        int n) {
    __shared__ float lsum[WIN];
    __shared__ int   lmax[WIN];
    __shared__ unsigned s_old;
    __shared__ float s_fa[4], s_fn[4];

    const int tid  = threadIdx.x;
    const int lane = tid & 63;

    const int chunk  = (n + NBLOCKS - 1) / NBLOCKS;   // 1954 for N=4M (even)
    const int cstart = blockIdx.x * chunk;

    if (cstart < n) {
        const int cend = min(cstart + chunk, n);
        const int base = cid[cstart];                 // broadcast load

        for (int j = tid; j < WIN; j += BLOCK) {
            lsum[j] = 0.0f;
            lmax[j] = (int)NEG_INF_BITS;
        }
        __syncthreads();

        // 2 nodes/thread; wave covers 128 consecutive nodes/iter.
        for (int i0 = cstart + tid * 2; __any(i0 < cend); i0 += BLOCK * 2) {
            bool v0 = (i0 < cend);
            bool v1 = (i0 + 1 < cend);
            float la = 0.0f, lb = 0.0f;
            int offa = -1, offb = -2;
            if (v0) {
                const float4* lg = reinterpret_cast<const float4*>(logits) + (size_t)i0 * 2;
                float4 a0 = lg[0];
                float4 a1 = lg[1];
                float4 b0, b1;
                int ta, tb = 0;
                if (v1) {
                    b0 = lg[2];
                    b1 = lg[3];
                    int2 tt = *reinterpret_cast<const int2*>(targets + i0);  // i0 even
                    int2 cc = *reinterpret_cast<const int2*>(cid + i0);
                    ta = tt.x; tb = tt.y;
                    offa = cc.x - base;
                    offb = cc.y - base;
                } else {
                    ta = targets[i0];
                    offa = cid[i0] - base;
                }
                la = node_focal(a0, a1, ta);
                if (v1) lb = node_focal(b0, b1, tb);
            }

            int u = __shfl(offa, 0);
            bool uniform = __all(offa == u && offb == u) && (u < WIN);
            if (uniform) {
                // all 128 nodes one segment: pair-combine then one butterfly
                float tsum = la + lb;
                float tmax = fmaxf(la, lb);
                #pragma unroll
                for (int o = 32; o > 0; o >>= 1) {
                    tsum += __shfl_xor(tsum, o);
                    tmax = fmaxf(tmax, __shfl_xor(tmax, o));
                }
                if (lane == 0) {
                    atomicAdd(&lsum[u], tsum);
                    atomicMax(&lmax[u], __float_as_int(tmax));
                }
            } else {
                if (v0) {
                    if (offa < WIN) {
                        atomicAdd(&lsum[offa], la);
                        atomicMax(&lmax[offa], __float_as_int(la));
                    } else {  // pathological overflow: direct global accumulate
                        atomicAdd(&seg_sum[base + offa], la);
                        atomicMax(&seg_maxb[base + offa], __float_as_uint(la));
                        atomicAdd(&seg_cnt[base + offa], 1u);
                    }
                }
                if (v1) {
                    if (offb < WIN) {
                        atomicAdd(&lsum[offb], lb);
                        atomicMax(&lmax[offb], __float_as_int(lb));
                    } else {
                        atomicAdd(&seg_sum[base + offb], lb);
                        atomicMax(&seg_maxb[base + offb], __float_as_uint(lb));
                        atomicAdd(&seg_cnt[base + offb], 1u);
                    }
                }
            }
        }
        __syncthreads();

        // flush touched window entries: ~5-10 global atomic triples per block
        for (int j = tid; j < WIN; j += BLOCK) {
            int mb = lmax[j];
            if (mb != (int)NEG_INF_BITS) {
                atomicAdd(&seg_sum[base + j], lsum[j]);
                atomicMax(&seg_maxb[base + j], (unsigned)mb);  // mb >= 0 bits
                atomicAdd(&seg_cnt[base + j], 1u);
            }
        }
    }

    // ---- ticket: last finished block runs the finalize (fence-free) ----
    // Explicit drain: all this wave's flush atomics acked at coherence point.
    asm volatile("s_waitcnt vmcnt(0)" ::: "memory");
    __syncthreads();              // all waves of block drained
    if (tid == 0) s_old = atomicAdd(ticket, 1u);
    __syncthreads();
    if (s_old == (unsigned)(NBLOCKS - 1)) {
        float acc = 0.0f, np = 0.0f;
        for (int k = tid; k < K_SEGS; k += BLOCK) {
            // device-scope atomic loads: read at coherence point (per-XCD L2
            // not cross-coherent; plain loads could hit stale lines)
            unsigned c = __hip_atomic_load(&seg_cnt[k], __ATOMIC_RELAXED, __HIP_MEMORY_SCOPE_AGENT);
            if (c != 0u) {
                float s    = __hip_atomic_load(&seg_sum[k],  __ATOMIC_RELAXED, __HIP_MEMORY_SCOPE_AGENT);
                unsigned m = __hip_atomic_load(&seg_maxb[k], __ATOMIC_RELAXED, __HIP_MEMORY_SCOPE_AGENT);
                acc += ALPHA_W * s + (1.0f - ALPHA_W) * __uint_as_float(m);
                np += 1.0f;
            }
        }
        #pragma unroll
        for (int o = 32; o > 0; o >>= 1) {
            acc += __shfl_xor(acc, o);
            np  += __shfl_xor(np, o);
        }
        if (lane == 0) { s_fa[tid >> 6] = acc; s_fn[tid >> 6] = np; }
        __syncthreads();
        if (tid == 0) {
            float a = s_fa[0] + s_fa[1] + s_fa[2] + s_fa[3];
            float c = s_fn[0] + s_fn[1] + s_fn[2] + s_fn[3];
            out[0] = a / fmaxf(c, 1.0f);
        }
    }
}

// ---------------------------------------------------------------------------
extern "C" void kernel_launch(void* const* d_in, const int* in_sizes, int n_in,
                              void* d_out, int out_size, void* d_ws, size_t ws_size,
                              hipStream_t stream) {
    const float* logits = (const float*)d_in[0];
    const int* targets  = (const int*)d_in[1];
    const int* cid      = (const int*)d_in[2];
    float* out          = (float*)d_out;

    const int n = in_sizes[1];   // N = 4,000,000

    unsigned* w        = (unsigned*)d_ws;
    float* seg_sum     = (float*)w;
    unsigned* seg_maxb = w + K_SEGS;
    unsigned* seg_cnt  = w + 2 * K_SEGS;
    unsigned* ticket   = w + 3 * K_SEGS;

    init_ws_kernel<<<(WS_WORDS + 255) / 256, 256, 0, stream>>>(w);

    node_loss_kernel<<<NBLOCKS, BLOCK, 0, stream>>>(logits, targets, cid,
                                                    seg_sum, seg_maxb, seg_cnt,
                                                    ticket, out, n);
}

// Round 10
// 55.889 us; speedup vs baseline: 4.5563x; 1.2110x over previous
//
#include <hip/hip_runtime.h>

#define K_SEGS 8192
#define ALPHA_W 0.5f
#define NEG_INF_BITS 0xFF800000
#define WIN 64            // id window per block (chunk spans ~5 ids; 64 = 12x margin)
#define NBLOCKS 2048
#define BLOCK 256
#define SHARD_SZ 32                       // blocks per ticket shard
#define NSHARDS (NBLOCKS / SHARD_SZ)      // 64 shards

// ws layout (unsigned words):
//   [0      .. 8191 ]   seg_sum  (float)
//   [8192   .. 16383]   seg_maxb (unsigned float-bits; init 0 valid since loss >= 0)
//   [16384  .. 24575]   seg_cnt  (unsigned; #blocks touching -> presence)
//   [24576  .. 24576+64*16-1]  shard tickets (one per 64B line)
//   [24576+64*16 .. +16]       stage2 ticket (own line)
#define SHARD_BASE (3 * K_SEGS)
#define STAGE2_OFF (SHARD_BASE + NSHARDS * 16)
#define WS_WORDS (STAGE2_OFF + 16)

// ---------------------------------------------------------------------------
// Kernel 0: zero accumulators + tickets (ws poisoned 0xAA, never re-poisoned)
// ---------------------------------------------------------------------------
__global__ void init_ws_kernel(unsigned* __restrict__ w) {
    int i = blockIdx.x * blockDim.x + threadIdx.x;
    if (i < WS_WORDS) w[i] = 0u;
}

// ---------------------------------------------------------------------------
// focal loss for one node given its 8 logits + target
// ---------------------------------------------------------------------------
__device__ __forceinline__ float node_focal(float4 a, float4 b, int t) {
    float x0 = a.x, x1 = a.y, x2 = a.z, x3 = a.w;
    float x4 = b.x, x5 = b.y, x6 = b.z, x7 = b.w;
    float m = fmaxf(fmaxf(fmaxf(x0, x1), fmaxf(x2, x3)),
                    fmaxf(fmaxf(x4, x5), fmaxf(x6, x7)));
    float s = __expf(x0 - m) + __expf(x1 - m) + __expf(x2 - m) + __expf(x3 - m)
            + __expf(x4 - m) + __expf(x5 - m) + __expf(x6 - m) + __expf(x7 - m);
    float lse = __logf(s) + m;
    float xt;
    switch (t) {
        case 0: xt = x0; break; case 1: xt = x1; break;
        case 2: xt = x2; break; case 3: xt = x3; break;
        case 4: xt = x4; break; case 5: xt = x5; break;
        case 6: xt = x6; break; default: xt = x7; break;
    }
    float ce = lse - xt;              // >= 0
    float pt = __expf(-ce);           // (0, 1]
    float om = 1.0f - pt;
    return om * om * ce;              // >= 0
}

// ---------------------------------------------------------------------------
// Kernel 1 (fused, fence-free, SHARDED ticket): focal loss + LDS-privatized
// segmented sum/max + last-block finalize. Cross-block traffic is device-scope
// atomics; vmcnt(0)+syncthreads orders flush -> ticket. Ticket is 64-way
// sharded (R9 lesson: 2048 atomics on ONE word = ~20us serialized drain).
// ---------------------------------------------------------------------------
__global__ __launch_bounds__(BLOCK) void node_loss_kernel(
        const float* __restrict__ logits,   // [N, 8]
        const int* __restrict__ targets,    // [N]
        const int* __restrict__ cid,        // [N], sorted
        float* __restrict__ seg_sum,        // [K]
        unsigned* __restrict__ seg_maxb,    // [K]
        unsigned* __restrict__ seg_cnt,     // [K]
        unsigned* __restrict__ shard_tk,    // [NSHARDS*16], one counter per line
        unsigned* __restrict__ stage2_tk,   // [16]
        float* __restrict__ out,
        int n) {
    __shared__ float lsum[WIN];
    __shared__ int   lmax[WIN];
    __shared__ unsigned s_last;
    __shared__ float s_fa[4], s_fn[4];

    const int tid  = threadIdx.x;
    const int lane = tid & 63;

    const int chunk  = (n + NBLOCKS - 1) / NBLOCKS;   // 1954 for N=4M (even)
    const int cstart = blockIdx.x * chunk;

    if (cstart < n) {
        const int cend = min(cstart + chunk, n);
        const int base = cid[cstart];                 // broadcast load

        for (int j = tid; j < WIN; j += BLOCK) {
            lsum[j] = 0.0f;
            lmax[j] = (int)NEG_INF_BITS;
        }
        __syncthreads();

        // 2 nodes/thread; wave covers 128 consecutive nodes/iter.
        for (int i0 = cstart + tid * 2; __any(i0 < cend); i0 += BLOCK * 2) {
            bool v0 = (i0 < cend);
            bool v1 = (i0 + 1 < cend);
            float la = 0.0f, lb = 0.0f;
            int offa = -1, offb = -2;
            if (v0) {
                const float4* lg = reinterpret_cast<const float4*>(logits) + (size_t)i0 * 2;
                float4 a0 = lg[0];
                float4 a1 = lg[1];
                float4 b0, b1;
                int ta, tb = 0;
                if (v1) {
                    b0 = lg[2];
                    b1 = lg[3];
                    int2 tt = *reinterpret_cast<const int2*>(targets + i0);  // i0 even
                    int2 cc = *reinterpret_cast<const int2*>(cid + i0);
                    ta = tt.x; tb = tt.y;
                    offa = cc.x - base;
                    offb = cc.y - base;
                } else {
                    ta = targets[i0];
                    offa = cid[i0] - base;
                }
                la = node_focal(a0, a1, ta);
                if (v1) lb = node_focal(b0, b1, tb);
            }

            int u = __shfl(offa, 0);
            bool uniform = __all(offa == u && offb == u) && (u < WIN);
            if (uniform) {
                // all 128 nodes one segment: pair-combine then one butterfly
                float tsum = la + lb;
                float tmax = fmaxf(la, lb);
                #pragma unroll
                for (int o = 32; o > 0; o >>= 1) {
                    tsum += __shfl_xor(tsum, o);
                    tmax = fmaxf(tmax, __shfl_xor(tmax, o));
                }
                if (lane == 0) {
                    atomicAdd(&lsum[u], tsum);
                    atomicMax(&lmax[u], __float_as_int(tmax));
                }
            } else {
                if (v0) {
                    if (offa < WIN) {
                        atomicAdd(&lsum[offa], la);
                        atomicMax(&lmax[offa], __float_as_int(la));
                    } else {  // pathological overflow: direct global accumulate
                        atomicAdd(&seg_sum[base + offa], la);
                        atomicMax(&seg_maxb[base + offa], __float_as_uint(la));
                        atomicAdd(&seg_cnt[base + offa], 1u);
                    }
                }
                if (v1) {
                    if (offb < WIN) {
                        atomicAdd(&lsum[offb], lb);
                        atomicMax(&lmax[offb], __float_as_int(lb));
                    } else {
                        atomicAdd(&seg_sum[base + offb], lb);
                        atomicMax(&seg_maxb[base + offb], __float_as_uint(lb));
                        atomicAdd(&seg_cnt[base + offb], 1u);
                    }
                }
            }
        }
        __syncthreads();

        // flush touched window entries: ~5-10 global atomic triples per block
        for (int j = tid; j < WIN; j += BLOCK) {
            int mb = lmax[j];
            if (mb != (int)NEG_INF_BITS) {
                atomicAdd(&seg_sum[base + j], lsum[j]);
                atomicMax(&seg_maxb[base + j], (unsigned)mb);  // mb >= 0 bits
                atomicAdd(&seg_cnt[base + j], 1u);
            }
        }
    }

    // ---- sharded ticket: last finished block overall runs the finalize ----
    asm volatile("s_waitcnt vmcnt(0)" ::: "memory");  // own flush atomics acked
    __syncthreads();                                  // whole block drained
    if (tid == 0) {
        unsigned fin = 0u;
        unsigned my = atomicAdd(&shard_tk[(blockIdx.x / SHARD_SZ) * 16], 1u);
        if (my == (unsigned)(SHARD_SZ - 1)) {
            // last block of this shard; all 32 of the shard's flushes are done
            fin = atomicAdd(&stage2_tk[0], 1u) + 1u;
        }
        s_last = (fin == (unsigned)NSHARDS) ? 1u : 0u;
    }
    __syncthreads();
    if (s_last) {
        float acc = 0.0f, np = 0.0f;
        for (int k = tid; k < K_SEGS; k += BLOCK) {
            // device-scope atomic loads: read at coherence point (per-XCD L2
            // not cross-coherent; plain loads could hit stale lines)
            unsigned c = __hip_atomic_load(&seg_cnt[k], __ATOMIC_RELAXED, __HIP_MEMORY_SCOPE_AGENT);
            if (c != 0u) {
                float s    = __hip_atomic_load(&seg_sum[k],  __ATOMIC_RELAXED, __HIP_MEMORY_SCOPE_AGENT);
                unsigned m = __hip_atomic_load(&seg_maxb[k], __ATOMIC_RELAXED, __HIP_MEMORY_SCOPE_AGENT);
                acc += ALPHA_W * s + (1.0f - ALPHA_W) * __uint_as_float(m);
                np += 1.0f;
            }
        }
        #pragma unroll
        for (int o = 32; o > 0; o >>= 1) {
            acc += __shfl_xor(acc, o);
            np  += __shfl_xor(np, o);
        }
        if (lane == 0) { s_fa[tid >> 6] = acc; s_fn[tid >> 6] = np; }
        __syncthreads();
        if (tid == 0) {
            float a = s_fa[0] + s_fa[1] + s_fa[2] + s_fa[3];
            float c = s_fn[0] + s_fn[1] + s_fn[2] + s_fn[3];
            out[0] = a / fmaxf(c, 1.0f);
        }
    }
}

// ---------------------------------------------------------------------------
extern "C" void kernel_launch(void* const* d_in, const int* in_sizes, int n_in,
                              void* d_out, int out_size, void* d_ws, size_t ws_size,
                              hipStream_t stream) {
    const float* logits = (const float*)d_in[0];
    const int* targets  = (const int*)d_in[1];
    const int* cid      = (const int*)d_in[2];
    float* out          = (float*)d_out;

    const int n = in_sizes[1];   // N = 4,000,000

    unsigned* w        = (unsigned*)d_ws;
    float* seg_sum     = (float*)w;
    unsigned* seg_maxb = w + K_SEGS;
    unsigned* seg_cnt  = w + 2 * K_SEGS;
    unsigned* shard_tk = w + SHARD_BASE;
    unsigned* stage2_tk= w + STAGE2_OFF;

    init_ws_kernel<<<(WS_WORDS + 255) / 256, 256, 0, stream>>>(w);

    node_loss_kernel<<<NBLOCKS, BLOCK, 0, stream>>>(logits, targets, cid,
                                                    seg_sum, seg_maxb, seg_cnt,
                                                    shard_tk, stage2_tk, out, n);
}

// Round 11
// 41.643 us; speedup vs baseline: 6.1150x; 1.3421x over previous
//
#include <hip/hip_runtime.h>

#define K_SEGS 8192
#define ALPHA_W 0.5f
#define NEG_INF_BITS 0xFF800000
#define WIN 64            // id window per block (chunk spans ~5 ids; 64 = 12x margin)
#define NBLOCKS 2048
#define BLOCK 256
#define SHARD_SZ 32                       // blocks per ticket shard
#define NSHARDS (NBLOCKS / SHARD_SZ)      // 64 shards

// ws layout (unsigned words):
//   [0      .. 8191 ]   seg_sum  (float)
//   [8192   .. 16383]   seg_maxb (unsigned float-bits; init 0 valid since loss >= 0)
//   [16384  .. 24575]   seg_cnt  (unsigned; #blocks touching -> presence)
//   [24576  .. 24576+64*16-1]  shard tickets (one per 64B line)
//   [24576+64*16 .. +16]       stage2 ticket (own line)
#define SHARD_BASE (3 * K_SEGS)
#define STAGE2_OFF (SHARD_BASE + NSHARDS * 16)
#define WS_WORDS (STAGE2_OFF + 16)

// ---------------------------------------------------------------------------
// Kernel 0: zero accumulators + tickets (ws poisoned 0xAA, never re-poisoned)
// ---------------------------------------------------------------------------
__global__ void init_ws_kernel(unsigned* __restrict__ w) {
    int i = blockIdx.x * blockDim.x + threadIdx.x;
    if (i < WS_WORDS) w[i] = 0u;
}

// ---------------------------------------------------------------------------
// focal loss for one node given its 8 logits + target
// ---------------------------------------------------------------------------
__device__ __forceinline__ float node_focal(float4 a, float4 b, int t) {
    float x0 = a.x, x1 = a.y, x2 = a.z, x3 = a.w;
    float x4 = b.x, x5 = b.y, x6 = b.z, x7 = b.w;
    float m = fmaxf(fmaxf(fmaxf(x0, x1), fmaxf(x2, x3)),
                    fmaxf(fmaxf(x4, x5), fmaxf(x6, x7)));
    float s = __expf(x0 - m) + __expf(x1 - m) + __expf(x2 - m) + __expf(x3 - m)
            + __expf(x4 - m) + __expf(x5 - m) + __expf(x6 - m) + __expf(x7 - m);
    float lse = __logf(s) + m;
    float xt;
    switch (t) {
        case 0: xt = x0; break; case 1: xt = x1; break;
        case 2: xt = x2; break; case 3: xt = x3; break;
        case 4: xt = x4; break; case 5: xt = x5; break;
        case 6: xt = x6; break; default: xt = x7; break;
    }
    float ce = lse - xt;              // >= 0
    float pt = __expf(-ce);           // (0, 1]
    float om = 1.0f - pt;
    return om * om * ce;              // >= 0
}

// ---------------------------------------------------------------------------
// Kernel 1 (fused, fence-free, sharded ticket, PIPELINED finalize):
// focal loss + LDS-privatized segmented sum/max + last-block finalize.
// R10 lesson: finalize tail was a ~40us one-block straggler because each
// iteration had a dependent c->(s,m) agent-load chain. Now all 3 loads are
// unconditional + unroll 8 -> ~24 independent loads in flight.
// ---------------------------------------------------------------------------
__global__ __launch_bounds__(BLOCK) void node_loss_kernel(
        const float* __restrict__ logits,   // [N, 8]
        const int* __restrict__ targets,    // [N]
        const int* __restrict__ cid,        // [N], sorted
        float* __restrict__ seg_sum,        // [K]
        unsigned* __restrict__ seg_maxb,    // [K]
        unsigned* __restrict__ seg_cnt,     // [K]
        unsigned* __restrict__ shard_tk,    // [NSHARDS*16], one counter per line
        unsigned* __restrict__ stage2_tk,   // [16]
        float* __restrict__ out,
        int n) {
    __shared__ float lsum[WIN];
    __shared__ int   lmax[WIN];
    __shared__ unsigned s_last;
    __shared__ float s_fa[4], s_fn[4];

    const int tid  = threadIdx.x;
    const int lane = tid & 63;

    const int chunk  = (n + NBLOCKS - 1) / NBLOCKS;   // 1954 for N=4M (even)
    const int cstart = blockIdx.x * chunk;

    if (cstart < n) {
        const int cend = min(cstart + chunk, n);
        const int base = cid[cstart];                 // broadcast load

        for (int j = tid; j < WIN; j += BLOCK) {
            lsum[j] = 0.0f;
            lmax[j] = (int)NEG_INF_BITS;
        }
        __syncthreads();

        // 2 nodes/thread; wave covers 128 consecutive nodes/iter.
        for (int i0 = cstart + tid * 2; __any(i0 < cend); i0 += BLOCK * 2) {
            bool v0 = (i0 < cend);
            bool v1 = (i0 + 1 < cend);
            float la = 0.0f, lb = 0.0f;
            int offa = -1, offb = -2;
            if (v0) {
                const float4* lg = reinterpret_cast<const float4*>(logits) + (size_t)i0 * 2;
                float4 a0 = lg[0];
                float4 a1 = lg[1];
                float4 b0, b1;
                int ta, tb = 0;
                if (v1) {
                    b0 = lg[2];
                    b1 = lg[3];
                    int2 tt = *reinterpret_cast<const int2*>(targets + i0);  // i0 even
                    int2 cc = *reinterpret_cast<const int2*>(cid + i0);
                    ta = tt.x; tb = tt.y;
                    offa = cc.x - base;
                    offb = cc.y - base;
                } else {
                    ta = targets[i0];
                    offa = cid[i0] - base;
                }
                la = node_focal(a0, a1, ta);
                if (v1) lb = node_focal(b0, b1, tb);
            }

            int u = __shfl(offa, 0);
            bool uniform = __all(offa == u && offb == u) && (u < WIN);
            if (uniform) {
                // all 128 nodes one segment: pair-combine then one butterfly
                float tsum = la + lb;
                float tmax = fmaxf(la, lb);
                #pragma unroll
                for (int o = 32; o > 0; o >>= 1) {
                    tsum += __shfl_xor(tsum, o);
                    tmax = fmaxf(tmax, __shfl_xor(tmax, o));
                }
                if (lane == 0) {
                    atomicAdd(&lsum[u], tsum);
                    atomicMax(&lmax[u], __float_as_int(tmax));
                }
            } else {
                if (v0) {
                    if (offa < WIN) {
                        atomicAdd(&lsum[offa], la);
                        atomicMax(&lmax[offa], __float_as_int(la));
                    } else {  // pathological overflow: direct global accumulate
                        atomicAdd(&seg_sum[base + offa], la);
                        atomicMax(&seg_maxb[base + offa], __float_as_uint(la));
                        atomicAdd(&seg_cnt[base + offa], 1u);
                    }
                }
                if (v1) {
                    if (offb < WIN) {
                        atomicAdd(&lsum[offb], lb);
                        atomicMax(&lmax[offb], __float_as_int(lb));
                    } else {
                        atomicAdd(&seg_sum[base + offb], lb);
                        atomicMax(&seg_maxb[base + offb], __float_as_uint(lb));
                        atomicAdd(&seg_cnt[base + offb], 1u);
                    }
                }
            }
        }
        __syncthreads();

        // flush touched window entries: ~5-10 global atomic triples per block
        for (int j = tid; j < WIN; j += BLOCK) {
            int mb = lmax[j];
            if (mb != (int)NEG_INF_BITS) {
                atomicAdd(&seg_sum[base + j], lsum[j]);
                atomicMax(&seg_maxb[base + j], (unsigned)mb);  // mb >= 0 bits
                atomicAdd(&seg_cnt[base + j], 1u);
            }
        }
    }

    // ---- sharded ticket: last finished block overall runs the finalize ----
    asm volatile("s_waitcnt vmcnt(0)" ::: "memory");  // own flush atomics acked
    __syncthreads();                                  // whole block drained
    if (tid == 0) {
        unsigned fin = 0u;
        unsigned my = atomicAdd(&shard_tk[(blockIdx.x / SHARD_SZ) * 16], 1u);
        if (my == (unsigned)(SHARD_SZ - 1)) {
            // last block of this shard; all 32 of the shard's flushes are done
            fin = atomicAdd(&stage2_tk[0], 1u) + 1u;
        }
        s_last = (fin == (unsigned)NSHARDS) ? 1u : 0u;
    }
    __syncthreads();
    if (s_last) {
        float acc = 0.0f, np = 0.0f;
        // Pipelined: all 3 agent-scope loads unconditional + unrolled so the
        // compiler can keep ~24 independent loads in flight (no c->(s,m) chain).
        #pragma unroll 8
        for (int k = tid; k < K_SEGS; k += BLOCK) {
            unsigned c = __hip_atomic_load(&seg_cnt[k],  __ATOMIC_RELAXED, __HIP_MEMORY_SCOPE_AGENT);
            float s    = __hip_atomic_load(&seg_sum[k],  __ATOMIC_RELAXED, __HIP_MEMORY_SCOPE_AGENT);
            unsigned m = __hip_atomic_load(&seg_maxb[k], __ATOMIC_RELAXED, __HIP_MEMORY_SCOPE_AGENT);
            if (c != 0u) {
                acc += ALPHA_W * s + (1.0f - ALPHA_W) * __uint_as_float(m);
                np += 1.0f;
            }
        }
        #pragma unroll
        for (int o = 32; o > 0; o >>= 1) {
            acc += __shfl_xor(acc, o);
            np  += __shfl_xor(np, o);
        }
        if (lane == 0) { s_fa[tid >> 6] = acc; s_fn[tid >> 6] = np; }
        __syncthreads();
        if (tid == 0) {
            float a = s_fa[0] + s_fa[1] + s_fa[2] + s_fa[3];
            float c = s_fn[0] + s_fn[1] + s_fn[2] + s_fn[3];
            out[0] = a / fmaxf(c, 1.0f);
        }
    }
}

// ---------------------------------------------------------------------------
extern "C" void kernel_launch(void* const* d_in, const int* in_sizes, int n_in,
                              void* d_out, int out_size, void* d_ws, size_t ws_size,
                              hipStream_t stream) {
    const float* logits = (const float*)d_in[0];
    const int* targets  = (const int*)d_in[1];
    const int* cid      = (const int*)d_in[2];
    float* out          = (float*)d_out;

    const int n = in_sizes[1];   // N = 4,000,000

    unsigned* w        = (unsigned*)d_ws;
    float* seg_sum     = (float*)w;
    unsigned* seg_maxb = w + K_SEGS;
    unsigned* seg_cnt  = w + 2 * K_SEGS;
    unsigned* shard_tk = w + SHARD_BASE;
    unsigned* stage2_tk= w + STAGE2_OFF;

    init_ws_kernel<<<(WS_WORDS + 255) / 256, 256, 0, stream>>>(w);

    node_loss_kernel<<<NBLOCKS, BLOCK, 0, stream>>>(logits, targets, cid,
                                                    seg_sum, seg_maxb, seg_cnt,
                                                    shard_tk, stage2_tk, out, n);
}